// Round 6
// baseline (299.374 us; speedup 1.0000x reference)
//
#include <hip/hip_runtime.h>

// QuantileLoss: scalar = ( sum_rows[ (p0-t0)^2+(p1-t1)^2+(p2-t2)^2 + 2*lower ] ) / (5N)
// lower = p3>p2 ? 1000 : (p3 > 0.95*t2 ? 0 : (p3-0.95*t2)^2)
//
// R1 bad-pattern, 54% occ:            ~101 us  (2.65 TB/s eff)
// R2 perfect-pattern LDS, 35% occ:    ~105 us  -> coalescing alone: no
// R3 NT registers, over-fetch:        ~150 us  (pins 2.68 TB/s)
// R4 NT+LDS+pipeline, 50% occ:        ~88 us   (3.05 TB/s eff, best)
// R5 global_load_lds, 50% occ:        ~103 us  -> VGPR-return-path: no
// Never tested: perfect pattern AND full occupancy together.
// R6: 512-row chunks -> 16 KB LDS -> 8 blocks/CU (100% occ), global_load_lds
// staging (wave-uniform base + lane*16; sp/st boundary 640 is 64-aligned so the
// array-select branch is wave-uniform), cached policy (let L3 serve its half).

#define NROWS 8388608                      // 2^23
#define ROWS_PER_CHUNK 512
#define NCHUNKS (NROWS / ROWS_PER_CHUNK)   // 16384
#define PCHUNK_F (ROWS_PER_CHUNK * 5)      // 2560 floats (10 KB)
#define TCHUNK_F (ROWS_PER_CHUNK * 3)      // 1536 floats (6 KB)
#define PCHUNK_F4 (PCHUNK_F / 4)           // 640
#define GRID 2048
#define CHUNKS_PER_BLOCK (NCHUNKS / GRID)  // 8

typedef float v4f __attribute__((ext_vector_type(4)));

__device__ __forceinline__ void async_copy16(const v4f* g, v4f* l)
{
    __builtin_amdgcn_global_load_lds(
        (const __attribute__((address_space(1))) void*)g,
        (__attribute__((address_space(3))) void*)l,
        16, 0, 0);
}

__global__ void __launch_bounds__(256) qloss_partial(
    const float* __restrict__ preds,
    const float* __restrict__ target,
    double* __restrict__ ws)
{
    __shared__ float sp[PCHUNK_F];
    __shared__ float st[TCHUNK_F];

    const int t = threadIdx.x;
    double acc = 0.0;

    for (int i = 0; i < CHUNKS_PER_BLOCK; ++i) {
        const int c = blockIdx.x + i * GRID;
        const v4f* gp = (const v4f*)(preds + (size_t)c * PCHUNK_F);
        const v4f* gt = (const v4f*)(target + (size_t)c * TCHUNK_F);

        // 4 float4 per thread across the 1024-float4 virtual concat [sp | st].
        // Boundary 640 is 64-aligned -> branch is wave-uniform; LDS dest is
        // wave-uniform base + lane*16 in both arms.
        #pragma unroll
        for (int k = 0; k < 4; ++k) {
            const int v = t + k * 256;
            if (v < PCHUNK_F4)
                async_copy16(gp + v, (v4f*)sp + v);
            else
                async_copy16(gt + (v - PCHUNK_F4), (v4f*)st + (v - PCHUNK_F4));
        }

        __syncthreads();   // vmcnt(0) drain + barrier

        // 2 rows per thread from LDS (stride 5/3: 2-way alias, free).
        float sum = 0.0f;
        #pragma unroll
        for (int rr = 0; rr < 2; ++rr) {
            const int r = t + rr * 256;
            const float p0 = sp[5*r + 0];
            const float p1 = sp[5*r + 1];
            const float p2 = sp[5*r + 2];
            const float p3 = sp[5*r + 3];
            const float t0 = st[3*r + 0];
            const float t1 = st[3*r + 1];
            const float t2 = st[3*r + 2];

            const float a0 = p0 - t0;
            const float a1 = p1 - t1;
            const float a2 = p2 - t2;
            const float m  = a0*a0 + a1*a1 + a2*a2;

            const float q = t2 * 0.95f;
            const float d = p3 - q;
            const float lower = (p3 > p2) ? 1000.0f : ((p3 > q) ? 0.0f : d * d);

            sum += m + 2.0f * lower;
        }
        acc += (double)sum;

        __syncthreads();   // LDS safe to overwrite
    }

    // wave64 shuffle reduce
    #pragma unroll
    for (int off = 32; off > 0; off >>= 1)
        acc += __shfl_down(acc, off, 64);

    __shared__ double red[4];
    const int lane = t & 63;
    const int wave = t >> 6;
    if (lane == 0) red[wave] = acc;
    __syncthreads();

    if (t == 0)
        atomicAdd(ws, red[0] + red[1] + red[2] + red[3]);   // 2048 atomics total
}

__global__ void qloss_final(const double* __restrict__ ws, float* __restrict__ out)
{
    *out = (float)(*ws / (5.0 * (double)NROWS));
}

extern "C" void kernel_launch(void* const* d_in, const int* in_sizes, int n_in,
                              void* d_out, int out_size, void* d_ws, size_t ws_size,
                              hipStream_t stream)
{
    const float* preds  = (const float*)d_in[0];
    const float* target = (const float*)d_in[1];
    float* out  = (float*)d_out;
    double* ws  = (double*)d_ws;

    // d_ws is re-poisoned to 0xAA before every timed launch — zero the accumulator.
    hipMemsetAsync(ws, 0, sizeof(double), stream);

    qloss_partial<<<GRID, 256, 0, stream>>>(preds, target, ws);
    qloss_final<<<1, 1, 0, stream>>>(ws, out);
}